// Round 4
// baseline (270.593 us; speedup 1.0000x reference)
//
#include <hip/hip_runtime.h>
#include <hip/hip_bf16.h>
#include <math.h>

#define BB 2
#define DIMC 256
#define FF 4
#define HH 16
#define WW 16
#define GRP 4
#define CPG 64        // DIM/GROUPS
#define ODIM 128      // OFF_DIMS
#define PQ 1024       // F*H*W
#define PJ 128        // FD*HD*WD
#define NBG 8         // B*GROUPS
#define INNERC 512

typedef short bf16x8 __attribute__((ext_vector_type(8)));
typedef float f32x4 __attribute__((ext_vector_type(4)));
typedef float f32x2 __attribute__((ext_vector_type(2)));

__device__ __forceinline__ unsigned int bfbits(float x) {
    union { float f; unsigned int u; } v; v.f = x;
    unsigned int u = v.u;
    unsigned int r = u + 0x7fffu + ((u >> 16) & 1u);
    return r >> 16;
}

__device__ __forceinline__ unsigned int pack_bf2(f32x2 a) {
    float2 ff = make_float2(a.x, a.y);
    __hip_bfloat162 h2 = __float22bfloat162_rn(ff);
    union { __hip_bfloat162 h; unsigned int u; } c; c.h = h2;
    return c.u;
}

// ---------------- q = grouped 1x1 conv, 4 outputs/thread ----------------
__global__ void k_q(const float* __restrict__ x, const float* __restrict__ wq,
                    float* __restrict__ q) {
    int t = blockIdx.x * blockDim.x + threadIdx.x;   // 8*32*1024 = 262144
    int p = t & 1023;
    int og = (t >> 10) & 31;
    int bg = t >> 15;
    int b = bg >> 2, g = bg & 3;
    int o0 = og * 4;
    const float* xp = x + (size_t)(b * DIMC + g * CPG) * PQ + p;
    const float* wp = wq + (size_t)(g * ODIM + o0) * CPG;
    float acc[4] = {0.f, 0.f, 0.f, 0.f};
    #pragma unroll 8
    for (int i = 0; i < CPG; ++i) {
        float xv = xp[i * PQ];
        #pragma unroll
        for (int k = 0; k < 4; ++k) acc[k] += xv * wp[k * CPG + i];
    }
    #pragma unroll
    for (int k = 0; k < 4; ++k)
        q[(size_t)(bg * ODIM + o0 + k) * PQ + p] = acc[k];
}

// ---------------- depthwise strided conv + GELU, plus W1 pack tail ----------------
__global__ void k_dwp(const float* __restrict__ q, const float* __restrict__ dww,
                      const float* __restrict__ dwb, float* __restrict__ act,
                      const float* __restrict__ w1, uint4* __restrict__ wb) {
    if (blockIdx.x >= 512) {
        int t = (blockIdx.x - 512) * 256 + threadIdx.x;
        if (t < 512) {
            int lane = t & 63, nt = (t >> 6) & 3, kc = t >> 8;
            int n = nt * 16 + (lane & 15);
            int kbase = kc * 32 + (lane >> 4) * 8;
            unsigned int pk[4];
            #pragma unroll
            for (int p = 0; p < 4; ++p) {
                unsigned int lo = bfbits(w1[(kbase + 2 * p) * 64 + n]);
                unsigned int hi = bfbits(w1[(kbase + 2 * p + 1) * 64 + n]);
                pk[p] = lo | (hi << 16);
            }
            wb[(kc * 4 + nt) * 64 + lane] = make_uint4(pk[0], pk[1], pk[2], pk[3]);
        }
        return;
    }
    int t = blockIdx.x * 256 + threadIdx.x;          // 8*128*128
    int j = t & 127;
    int c = (t >> 7) & 127;
    int bg = t >> 14;
    int xo = j & 7, yo = (j >> 3) & 7, zo = j >> 6;
    const float* qp = q + (size_t)(bg * ODIM + c) * PQ;
    const float* wp = dww + c * 64;
    float acc = dwb[c];
    #pragma unroll
    for (int kz = 0; kz < 4; ++kz) {
        int z = 2 * zo - 1 + kz;
        if (z < 0 || z >= FF) continue;
        #pragma unroll
        for (int ky = 0; ky < 4; ++ky) {
            int y = 2 * yo - 1 + ky;
            if (y < 0 || y >= HH) continue;
            #pragma unroll
            for (int kx = 0; kx < 4; ++kx) {
                int xx = 2 * xo - 1 + kx;
                if (xx < 0 || xx >= WW) continue;
                acc += qp[(z * HH + y) * WW + xx] * wp[(kz * 4 + ky) * 4 + kx];
            }
        }
    }
    act[t] = 0.5f * acc * (1.0f + erff(acc * 0.70710678118654752f));
}

// ------- fused: offsets (1x1 conv reduce + tanh) -> grid -> trilinear sample -> k/v proj
// one block per (bg, j); 128 threads
__global__ __launch_bounds__(128) void k_kvf(
    const float* __restrict__ act, const float* __restrict__ pw,
    const float* __restrict__ x, const float* __restrict__ wk,
    const float* __restrict__ wv, float* __restrict__ gkv,
    float* __restrict__ kk2, float* __restrict__ vvT2) {
    __shared__ float red2[6];
    __shared__ float crd[3];
    __shared__ float kvs[64];
    int blk = blockIdx.x;            // bg*128 + j
    int j = blk & 127, bg = blk >> 7;
    int b = bg >> 2, g = bg & 3;
    int tid = threadIdx.x, w = tid >> 6;

    // phase 1: pointwise 3x128 reduction
    float val = act[(size_t)(bg * ODIM + tid) * PJ + j];
    float s0 = val * pw[tid];
    float s1 = val * pw[ODIM + tid];
    float s2 = val * pw[2 * ODIM + tid];
    #pragma unroll
    for (int off = 32; off; off >>= 1) {
        s0 += __shfl_xor(s0, off);
        s1 += __shfl_xor(s1, off);
        s2 += __shfl_xor(s2, off);
    }
    if ((tid & 63) == 0) { red2[w * 3] = s0; red2[w * 3 + 1] = s1; red2[w * 3 + 2] = s2; }
    __syncthreads();
    if (tid == 0) {
        s0 = red2[0] + red2[3]; s1 = red2[1] + red2[4]; s2 = red2[2] + red2[5];
        float xo = (float)(j & 7), yo = (float)((j >> 3) & 7), zo = (float)(j >> 6);
        float vf = zo + 2.f * tanhf(s0);
        float vh = yo + 2.f * tanhf(s1);
        float vw = xo + 2.f * tanhf(s2);
        float c0 = 2.f * vf - 1.f;
        float c1 = 2.f * vh / 7.f - 1.f;
        float c2 = 2.f * vw / 7.f - 1.f;
        crd[0] = c0; crd[1] = c1; crd[2] = c2;
        gkv[blk * 3 + 0] = c0; gkv[blk * 3 + 1] = c1; gkv[blk * 3 + 2] = c2;
    }
    __syncthreads();

    // phase 2: trilinear sample, channel tid (wave 0 only)
    // BUG-COMPATIBLE: crd[0] (f-coord) -> x/W axis, crd[1] -> y/H, crd[2] (w) -> z/D.
    if (tid < 64) {
        float ix = ((crd[0] + 1.f) * WW - 1.f) * 0.5f;
        float iy = ((crd[1] + 1.f) * HH - 1.f) * 0.5f;
        float iz = ((crd[2] + 1.f) * FF - 1.f) * 0.5f;
        float x0f = floorf(ix), y0f = floorf(iy), z0f = floorf(iz);
        float tx = ix - x0f, ty = iy - y0f, tz = iz - z0f;
        int x0 = (int)x0f, y0 = (int)y0f, z0 = (int)z0f;
        const float* vol = x + (size_t)(b * DIMC + g * CPG + tid) * PQ;
        float acc = 0.f;
        #pragma unroll
        for (int dz = 0; dz < 2; ++dz) {
            int zc = z0 + dz;
            if (zc < 0 || zc >= FF) continue;
            float wz = dz ? tz : 1.f - tz;
            #pragma unroll
            for (int dy = 0; dy < 2; ++dy) {
                int yc = y0 + dy;
                if (yc < 0 || yc >= HH) continue;
                float wy = dy ? ty : 1.f - ty;
                #pragma unroll
                for (int dx = 0; dx < 2; ++dx) {
                    int xc = x0 + dx;
                    if (xc < 0 || xc >= WW) continue;
                    float wgt = wz * wy * (dx ? tx : 1.f - tx);
                    acc += vol[(zc * HH + yc) * WW + xc] * wgt;
                }
            }
        }
        kvs[tid] = acc;
    }
    __syncthreads();

    // phase 3: k/v projection, output channel o = tid
    const float* wkp = wk + (size_t)(g * ODIM + tid) * CPG;
    const float* wvp = wv + (size_t)(g * ODIM + tid) * CPG;
    float ak = 0.f, av = 0.f;
    #pragma unroll
    for (int i = 0; i < 64; i += 4) {
        float4 kv4 = *(const float4*)&kvs[i];
        float4 wk4 = *(const float4*)&wkp[i];
        float4 wv4 = *(const float4*)&wvp[i];
        ak += kv4.x * wk4.x + kv4.y * wk4.y + kv4.z * wk4.z + kv4.w * wk4.w;
        av += kv4.x * wv4.x + kv4.y * wv4.y + kv4.z * wv4.z + kv4.w * wv4.w;
    }
    kk2[((size_t)(bg * 64 + (tid & 63)) * PJ + j) * 2 + (tid >> 6)] = ak;
    vvT2[((size_t)(bg * 64 + (j >> 1)) * ODIM + tid) * 2 + (j & 1)] = av;
}

// ---------------- fused CPB MLP (MFMA) + QK^T + softmax + attn*V, 4 queries/block ----
__global__ __launch_bounds__(128) void k_attn(
    const float* __restrict__ q, const float* __restrict__ kk2,
    const float* __restrict__ vvT2, const float* __restrict__ gkv,
    const float* __restrict__ w0, const float* __restrict__ b0,
    const uint4* __restrict__ wb, const float* __restrict__ b1,
    const float* __restrict__ w2, const float* __restrict__ b2,
    float* __restrict__ outh) {
    // h0s [8][128] uint4 (16384 B) aliased with part [128][17] f32x2 (17408 B)
    __shared__ __align__(16) char buf_[17408];
    uint4* h0s = (uint4*)buf_;
    f32x2* part = (f32x2*)buf_;
    __shared__ float qsL[512];       // [ii][d*2+e]
    __shared__ float attL[1024];     // [ii][head][j]
    __shared__ float redA[16];

    int blk = blockIdx.x;            // bg*256 + it
    int it = blk & 255, bg = blk >> 8;
    int i0 = it * 4;
    int b = bg >> 2, g = bg & 3;
    int tid = threadIdx.x;           // 0..127
    int w = tid >> 6, lane = tid & 63, col = lane & 15, quad = lane >> 4;
    int j = tid;

    // W1 B fragments (block-invariant, L2-hot)
    uint4 bfr[2][4];
    #pragma unroll
    for (int kc = 0; kc < 2; ++kc)
        #pragma unroll
        for (int nt = 0; nt < 4; ++nt)
            bfr[kc][nt] = wb[(kc * 4 + nt) * 64 + lane];

    // stage 4 q-vectors (float4 over consecutive i)
    {
        float4 q4 = *(const float4*)(q + (size_t)(bg * ODIM + tid) * PQ + i0);
        int e = tid >> 6, d = tid & 63;
        qsL[0 * 128 + d * 2 + e] = q4.x * 0.125f;
        qsL[1 * 128 + d * 2 + e] = q4.y * 0.125f;
        qsL[2 * 128 + d * 2 + e] = q4.z * 0.125f;
        qsL[3 * 128 + d * 2 + e] = q4.w * 0.125f;
    }

    float g0j = gkv[(bg * PJ + j) * 3 + 0];
    float g1j = gkv[(bg * PJ + j) * 3 + 1];
    float g2j = gkv[(bg * PJ + j) * 3 + 2];

    float b1v[4]; f32x2 w2v[4];
    #pragma unroll
    for (int nt = 0; nt < 4; ++nt) {
        int jj = nt * 16 + col;
        b1v[nt] = b1[jj];
        w2v[nt] = *(const f32x2*)&w2[jj * 2];
    }
    f32x2 bias_b2 = *(const f32x2*)b2;

    f32x2 sc[4];

    // ---- 4 CPB sub-rounds ----
    for (int ii = 0; ii < 4; ++ii) {
        int i = i0 + ii;
        int wq_ = i & 15, hq = (i >> 4) & 15, fq = i >> 8;
        float p0 = (2.f * fq / 3.f - 1.f)  - g0j;
        float p1 = (2.f * hq / 15.f - 1.f) - g1j;
        float p2 = (2.f * wq_ / 15.f - 1.f) - g2j;
        float t0 = copysignf(__logf(1.f + fabsf(p0)), p0);
        float t1 = copysignf(__logf(1.f + fabsf(p1)), p1);
        float t2 = copysignf(__logf(1.f + fabsf(p2)), p2);

        #pragma unroll
        for (int c = 0; c < 8; ++c) {
            unsigned int pk[4];
            #pragma unroll
            for (int hp = 0; hp < 4; ++hp) {
                int k2 = c * 8 + hp * 2;
                f32x2 a = *(const f32x2*)&b0[k2];
                a += t0 * *(const f32x2*)&w0[k2];
                a += t1 * *(const f32x2*)&w0[64 + k2];
                a += t2 * *(const f32x2*)&w0[128 + k2];
                a.x = fmaxf(a.x, 0.f); a.y = fmaxf(a.y, 0.f);
                pk[hp] = pack_bf2(a);
            }
            h0s[c * 128 + j] = make_uint4(pk[0], pk[1], pk[2], pk[3]);
        }
        __syncthreads();

        f32x4 acc[4][4] = {};
        #pragma unroll
        for (int kc = 0; kc < 2; ++kc)
            #pragma unroll
            for (int mt = 0; mt < 4; ++mt) {
                uint4 avv = h0s[(kc * 4 + quad) * 128 + (w * 64 + mt * 16 + col)];
                bf16x8 af = *(bf16x8*)&avv;
                #pragma unroll
                for (int nt = 0; nt < 4; ++nt)
                    acc[mt][nt] = __builtin_amdgcn_mfma_f32_16x16x32_bf16(
                        af, *(bf16x8*)&bfr[kc][nt], acc[mt][nt], 0, 0, 0);
            }
        __syncthreads();   // h0s reads done -> alias as part[]

        #pragma unroll
        for (int mt = 0; mt < 4; ++mt)
            #pragma unroll
            for (int reg = 0; reg < 4; ++reg) {
                f32x2 pp = {0.f, 0.f};
                #pragma unroll
                for (int nt = 0; nt < 4; ++nt) {
                    float hv = fmaxf(acc[mt][nt][reg] + b1v[nt], 0.f);
                    pp += hv * w2v[nt];
                }
                int m = w * 64 + mt * 16 + quad * 4 + reg;
                part[m * 17 + col] = pp;
            }
        __syncthreads();

        f32x2 bias2 = bias_b2;
        {
            const f32x2* pr = &part[j * 17];
            #pragma unroll
            for (int c = 0; c < 16; ++c) bias2 += pr[c];
        }
        sc[ii] = bias2;
        __syncthreads();   // part reads done before next round's h0s writes
    }

    // ---- QK^T batched over 4 i's ----
    {
        const f32x2* kp = (const f32x2*)kk2 + (size_t)(bg * 64) * PJ + j;
        #pragma unroll 4
        for (int d = 0; d < 64; ++d) {
            f32x2 kv2 = kp[(size_t)d * PJ];
            #pragma unroll
            for (int ii = 0; ii < 4; ++ii) {
                f32x2 qv = *(const f32x2*)&qsL[ii * 128 + d * 2];
                sc[ii] += qv * kv2;
            }
        }
    }
    #pragma unroll
    for (int ii = 0; ii < 4; ++ii) {
        attL[ii * 256 + j] = sc[ii].x;
        attL[ii * 256 + 128 + j] = sc[ii].y;
    }
    __syncthreads();

    // softmax reduce: wave w handles head w, loop ii
    #pragma unroll
    for (int ii = 0; ii < 4; ++ii) {
        float a0 = attL[ii * 256 + w * 128 + lane];
        float a1 = attL[ii * 256 + w * 128 + 64 + lane];
        float mx = fmaxf(a0, a1);
        #pragma unroll
        for (int off = 32; off; off >>= 1) mx = fmaxf(mx, __shfl_xor(mx, off));
        float ex = __expf(a0 - mx) + __expf(a1 - mx);
        #pragma unroll
        for (int off = 32; off; off >>= 1) ex += __shfl_xor(ex, off);
        if (lane == 0) { redA[ii * 4 + w * 2] = mx; redA[ii * 4 + w * 2 + 1] = ex; }
    }
    __syncthreads();
    #pragma unroll
    for (int ii = 0; ii < 4; ++ii) {
        float p0n = __expf(sc[ii].x - redA[ii * 4 + 0]) * (1.f / redA[ii * 4 + 1]);
        float p1n = __expf(sc[ii].y - redA[ii * 4 + 2]) * (1.f / redA[ii * 4 + 3]);
        attL[ii * 256 + j] = p0n;
        attL[ii * 256 + 128 + j] = p1n;
    }
    __syncthreads();

    // ---- attn * V batched: thread (e=w, d=lane), V row reused 4x ----
    {
        const f32x2* vp = (const f32x2*)vvT2 + (size_t)(bg * 64) * ODIM + tid;
        f32x2 oacc[4] = {};
        #pragma unroll 4
        for (int jp = 0; jp < 64; ++jp) {
            f32x2 vv2 = vp[(size_t)jp * ODIM];
            #pragma unroll
            for (int ii = 0; ii < 4; ++ii) {
                f32x2 ap2 = *(const f32x2*)&attL[ii * 256 + w * 128 + jp * 2];
                oacc[ii] += ap2 * vv2;
            }
        }
        #pragma unroll
        for (int ii = 0; ii < 4; ++ii)
            outh[((size_t)b * PQ + i0 + ii) * INNERC + g * 128 + tid] =
                oacc[ii].x + oacc[ii].y;
    }
}

// ---------------- final projection, 8 outputs/thread, contiguous reads ---------
__global__ void k_out(const float* __restrict__ outh, const float* __restrict__ wo,
                      const float* __restrict__ bo, float* __restrict__ out) {
    int t = blockIdx.x * 256 + threadIdx.x;   // 2*32*1024 = 65536
    int p = t & 1023;
    int og = (t >> 10) & 31;
    int b = t >> 15;
    int o0 = og * 8;
    const float* hp = outh + ((size_t)b * PQ + p) * INNERC;
    const float* wp = wo + (size_t)o0 * INNERC;
    float acc[8];
    #pragma unroll
    for (int k = 0; k < 8; ++k) acc[k] = bo[o0 + k];
    #pragma unroll 4
    for (int c = 0; c < INNERC; c += 4) {
        float4 hv = *(const float4*)&hp[c];
        #pragma unroll
        for (int k = 0; k < 8; ++k) {
            const float* wr = &wp[k * INNERC + c];
            acc[k] += hv.x * wr[0] + hv.y * wr[1] + hv.z * wr[2] + hv.w * wr[3];
        }
    }
    #pragma unroll
    for (int k = 0; k < 8; ++k)
        out[(size_t)(b * DIMC + o0 + k) * PQ + p] = acc[k];
}

extern "C" void kernel_launch(void* const* d_in, const int* in_sizes, int n_in,
                              void* d_out, int out_size, void* d_ws, size_t ws_size,
                              hipStream_t stream) {
    const float* x   = (const float*)d_in[0];
    const float* wq  = (const float*)d_in[1];
    const float* wk  = (const float*)d_in[2];
    const float* wv  = (const float*)d_in[3];
    const float* dww = (const float*)d_in[4];
    const float* dwb = (const float*)d_in[5];
    const float* pw  = (const float*)d_in[6];
    const float* w0  = (const float*)d_in[7];
    const float* b0  = (const float*)d_in[8];
    const float* w1  = (const float*)d_in[9];
    const float* b1  = (const float*)d_in[10];
    const float* w2  = (const float*)d_in[11];
    const float* b2  = (const float*)d_in[12];
    const float* wo  = (const float*)d_in[13];
    const float* bo  = (const float*)d_in[14];
    float* out = (float*)d_out;

    float* ws_f = (float*)d_ws;
    uint4* wb   = (uint4*)ws_f;          // 2048 floats
    float* q    = ws_f + 2048;           // 1048576
    float* act  = q + 1048576;           // 131072
    float* gkv  = act + 131072;          // 3072
    float* kk2  = gkv + 3072;            // 131072
    float* vvT2 = kk2 + 131072;          // 131072
    float* outh = vvT2 + 131072;         // 1048576

    k_q<<<1024, 256, 0, stream>>>(x, wq, q);
    k_dwp<<<514, 256, 0, stream>>>(q, dww, dwb, act, w1, wb);
    k_kvf<<<1024, 128, 0, stream>>>(act, pw, x, wk, wv, gkv, kk2, vvT2);
    k_attn<<<2048, 128, 0, stream>>>(q, kk2, vvT2, gkv, w0, b0, wb, b1, w2, b2, outh);
    k_out<<<256, 256, 0, stream>>>(outh, wo, bo, out);
}

// Round 5
// 265.027 us; speedup vs baseline: 1.0210x; 1.0210x over previous
//
#include <hip/hip_runtime.h>
#include <hip/hip_bf16.h>
#include <math.h>

#define BB 2
#define DIMC 256
#define FF 4
#define HH 16
#define WW 16
#define GRP 4
#define CPG 64        // DIM/GROUPS
#define ODIM 128      // OFF_DIMS
#define PQ 1024       // F*H*W
#define PJ 128        // FD*HD*WD
#define NBG 8         // B*GROUPS
#define INNERC 512

typedef short bf16x8 __attribute__((ext_vector_type(8)));
typedef float f32x4 __attribute__((ext_vector_type(4)));
typedef float f32x2 __attribute__((ext_vector_type(2)));

__device__ __forceinline__ unsigned int bfbits(float x) {
    union { float f; unsigned int u; } v; v.f = x;
    unsigned int u = v.u;
    unsigned int r = u + 0x7fffu + ((u >> 16) & 1u);
    return r >> 16;
}

__device__ __forceinline__ unsigned int pack_bf2(f32x2 a) {
    float2 ff = make_float2(a.x, a.y);
    __hip_bfloat162 h2 = __float22bfloat162_rn(ff);
    union { __hip_bfloat162 h; unsigned int u; } c; c.h = h2;
    return c.u;
}

// ---- fused: q = grouped 1x1 conv (kept in LDS + written out) -> depthwise conv + GELU
// blocks 0..255: (bg, og) where og = 4-channel group; blocks 256..257: W1 bf16 pack
__global__ __launch_bounds__(256) void k_qdw(
    const float* __restrict__ x, const float* __restrict__ wq,
    const float* __restrict__ dww, const float* __restrict__ dwb,
    const float* __restrict__ w1,
    float* __restrict__ q, float* __restrict__ act, uint4* __restrict__ wb) {
    if (blockIdx.x >= 256) {
        int t = (blockIdx.x - 256) * 256 + threadIdx.x;
        if (t < 512) {
            int lane = t & 63, nt = (t >> 6) & 3, kc = t >> 8;
            int n = nt * 16 + (lane & 15);
            int kbase = kc * 32 + (lane >> 4) * 8;
            unsigned int pk[4];
            #pragma unroll
            for (int p = 0; p < 4; ++p) {
                unsigned int lo = bfbits(w1[(kbase + 2 * p) * 64 + n]);
                unsigned int hi = bfbits(w1[(kbase + 2 * p + 1) * 64 + n]);
                pk[p] = lo | (hi << 16);
            }
            wb[(kc * 4 + nt) * 64 + lane] = make_uint4(pk[0], pk[1], pk[2], pk[3]);
        }
        return;
    }
    __shared__ float qs[4][1024];    // 16 KB
    int og = blockIdx.x & 31, bg = blockIdx.x >> 5;
    int b = bg >> 2, g = bg & 3;
    int o0 = og * 4;
    int tid = threadIdx.x;
    const float* xp = x + (size_t)(b * DIMC + g * CPG) * PQ;
    const float* wp = wq + (size_t)(g * ODIM + o0) * CPG;

    float accq[4][4] = {};
    #pragma unroll 4
    for (int i = 0; i < CPG; ++i) {
        float wv[4];
        #pragma unroll
        for (int k = 0; k < 4; ++k) wv[k] = wp[k * CPG + i];
        #pragma unroll
        for (int pi = 0; pi < 4; ++pi) {
            float xv = xp[(size_t)i * PQ + tid + pi * 256];
            #pragma unroll
            for (int k = 0; k < 4; ++k) accq[pi][k] += xv * wv[k];
        }
    }
    #pragma unroll
    for (int pi = 0; pi < 4; ++pi)
        #pragma unroll
        for (int k = 0; k < 4; ++k) {
            int p = tid + pi * 256;
            qs[k][p] = accq[pi][k];
            q[(size_t)(bg * ODIM + o0 + k) * PQ + p] = accq[pi][k];
        }
    __syncthreads();

    #pragma unroll
    for (int r = 0; r < 2; ++r) {
        int s = tid + r * 256;
        int cl = s >> 7, j = s & 127;
        int c = o0 + cl;
        int xo = j & 7, yo = (j >> 3) & 7, zo = j >> 6;
        const float* wd = dww + c * 64;
        float acc = dwb[c];
        #pragma unroll
        for (int kz = 0; kz < 4; ++kz) {
            int z = 2 * zo - 1 + kz;
            if (z < 0 || z >= FF) continue;
            #pragma unroll
            for (int ky = 0; ky < 4; ++ky) {
                int y = 2 * yo - 1 + ky;
                if (y < 0 || y >= HH) continue;
                #pragma unroll
                for (int kx = 0; kx < 4; ++kx) {
                    int xx = 2 * xo - 1 + kx;
                    if (xx < 0 || xx >= WW) continue;
                    acc += qs[cl][(z * HH + y) * WW + xx] * wd[(kz * 4 + ky) * 4 + kx];
                }
            }
        }
        act[((size_t)bg * ODIM + c) * PJ + j] =
            0.5f * acc * (1.0f + erff(acc * 0.70710678118654752f));
    }
}

// ------- fused: offsets (1x1 conv reduce + tanh) -> grid -> trilinear sample -> k/v proj
__global__ __launch_bounds__(128) void k_kvf(
    const float* __restrict__ act, const float* __restrict__ pw,
    const float* __restrict__ x, const float* __restrict__ wk,
    const float* __restrict__ wv, float* __restrict__ gkv,
    float* __restrict__ kk2, float* __restrict__ vvT2) {
    __shared__ float red2[6];
    __shared__ float crd[3];
    __shared__ float kvs[64];
    int blk = blockIdx.x;            // bg*128 + j
    int j = blk & 127, bg = blk >> 7;
    int b = bg >> 2, g = bg & 3;
    int tid = threadIdx.x, w = tid >> 6;

    float val = act[(size_t)(bg * ODIM + tid) * PJ + j];
    float s0 = val * pw[tid];
    float s1 = val * pw[ODIM + tid];
    float s2 = val * pw[2 * ODIM + tid];
    #pragma unroll
    for (int off = 32; off; off >>= 1) {
        s0 += __shfl_xor(s0, off);
        s1 += __shfl_xor(s1, off);
        s2 += __shfl_xor(s2, off);
    }
    if ((tid & 63) == 0) { red2[w * 3] = s0; red2[w * 3 + 1] = s1; red2[w * 3 + 2] = s2; }
    __syncthreads();
    if (tid == 0) {
        s0 = red2[0] + red2[3]; s1 = red2[1] + red2[4]; s2 = red2[2] + red2[5];
        float xo = (float)(j & 7), yo = (float)((j >> 3) & 7), zo = (float)(j >> 6);
        float vf = zo + 2.f * tanhf(s0);
        float vh = yo + 2.f * tanhf(s1);
        float vw = xo + 2.f * tanhf(s2);
        float c0 = 2.f * vf - 1.f;
        float c1 = 2.f * vh / 7.f - 1.f;
        float c2 = 2.f * vw / 7.f - 1.f;
        crd[0] = c0; crd[1] = c1; crd[2] = c2;
        gkv[blk * 3 + 0] = c0; gkv[blk * 3 + 1] = c1; gkv[blk * 3 + 2] = c2;
    }
    __syncthreads();

    // BUG-COMPATIBLE: crd[0] (f-coord) -> x/W axis, crd[1] -> y/H, crd[2] (w) -> z/D.
    if (tid < 64) {
        float ix = ((crd[0] + 1.f) * WW - 1.f) * 0.5f;
        float iy = ((crd[1] + 1.f) * HH - 1.f) * 0.5f;
        float iz = ((crd[2] + 1.f) * FF - 1.f) * 0.5f;
        float x0f = floorf(ix), y0f = floorf(iy), z0f = floorf(iz);
        float tx = ix - x0f, ty = iy - y0f, tz = iz - z0f;
        int x0 = (int)x0f, y0 = (int)y0f, z0 = (int)z0f;
        const float* vol = x + (size_t)(b * DIMC + g * CPG + tid) * PQ;
        float acc = 0.f;
        #pragma unroll
        for (int dz = 0; dz < 2; ++dz) {
            int zc = z0 + dz;
            if (zc < 0 || zc >= FF) continue;
            float wz = dz ? tz : 1.f - tz;
            #pragma unroll
            for (int dy = 0; dy < 2; ++dy) {
                int yc = y0 + dy;
                if (yc < 0 || yc >= HH) continue;
                float wy = dy ? ty : 1.f - ty;
                #pragma unroll
                for (int dx = 0; dx < 2; ++dx) {
                    int xc = x0 + dx;
                    if (xc < 0 || xc >= WW) continue;
                    float wgt = wz * wy * (dx ? tx : 1.f - tx);
                    acc += vol[(zc * HH + yc) * WW + xc] * wgt;
                }
            }
        }
        kvs[tid] = acc;
    }
    __syncthreads();

    const float* wkp = wk + (size_t)(g * ODIM + tid) * CPG;
    const float* wvp = wv + (size_t)(g * ODIM + tid) * CPG;
    float ak = 0.f, av = 0.f;
    #pragma unroll
    for (int i = 0; i < 64; i += 4) {
        float4 kv4 = *(const float4*)&kvs[i];
        float4 wk4 = *(const float4*)&wkp[i];
        float4 wv4 = *(const float4*)&wvp[i];
        ak += kv4.x * wk4.x + kv4.y * wk4.y + kv4.z * wk4.z + kv4.w * wk4.w;
        av += kv4.x * wv4.x + kv4.y * wv4.y + kv4.z * wv4.z + kv4.w * wv4.w;
    }
    kk2[((size_t)(bg * 64 + (tid & 63)) * PJ + j) * 2 + (tid >> 6)] = ak;
    vvT2[((size_t)(bg * 64 + (j >> 1)) * ODIM + tid) * 2 + (j & 1)] = av;
}

// ---- fused CPB (barrier-free MFMA, M-dim = j) + QK^T + softmax + attn*V, 4 queries/block
__global__ __launch_bounds__(128) void k_attn(
    const float* __restrict__ q, const float* __restrict__ kk2,
    const float* __restrict__ vvT2, const float* __restrict__ gkv,
    const float* __restrict__ w0, const float* __restrict__ b0,
    const uint4* __restrict__ wb, const float* __restrict__ b1,
    const float* __restrict__ w2, const float* __restrict__ b2,
    float* __restrict__ outh) {
    // tbuf: per-wave transpose buffers (64 rows x 17 f32x2 each); attL aliases wave0's region
    __shared__ __align__(16) float tbuf[2 * 2176];   // 17408 B
    __shared__ float qsL[512];
    __shared__ float redA[16];
    float* attL = tbuf;              // 1024 floats, used only after post-CPB barrier

    int blk = blockIdx.x;            // bg*256 + it
    int it = blk & 255, bg = blk >> 8;
    int i0 = it * 4;
    int b = bg >> 2, g = bg & 3;
    int tid = threadIdx.x;
    int w = tid >> 6, lane = tid & 63, col = lane & 15, quad = lane >> 4;
    int j = tid;

    // W1 B fragments (block-invariant, L2-hot)
    uint4 bfr[2][4];
    #pragma unroll
    for (int kc = 0; kc < 2; ++kc)
        #pragma unroll
        for (int nt = 0; nt < 4; ++nt)
            bfr[kc][nt] = wb[(kc * 4 + nt) * 64 + lane];

    // stage 4 q-vectors
    {
        float4 q4 = *(const float4*)(q + (size_t)(bg * ODIM + tid) * PQ + i0);
        int e = tid >> 6, d = tid & 63;
        qsL[0 * 128 + d * 2 + e] = q4.x * 0.125f;
        qsL[1 * 128 + d * 2 + e] = q4.y * 0.125f;
        qsL[2 * 128 + d * 2 + e] = q4.z * 0.125f;
        qsL[3 * 128 + d * 2 + e] = q4.w * 0.125f;
    }

    // per-lane key coords for its 4 A-tile rows: j_r = w*64 + mt*16 + col
    float g0r[4], g1r[4], g2r[4];
    #pragma unroll
    for (int mt = 0; mt < 4; ++mt) {
        int jr = w * 64 + mt * 16 + col;
        g0r[mt] = gkv[(bg * PJ + jr) * 3 + 0];
        g1r[mt] = gkv[(bg * PJ + jr) * 3 + 1];
        g2r[mt] = gkv[(bg * PJ + jr) * 3 + 2];
    }

    float b1v[4]; f32x2 w2v[4];
    #pragma unroll
    for (int nt = 0; nt < 4; ++nt) {
        int jj = nt * 16 + col;
        b1v[nt] = b1[jj];
        w2v[nt] = *(const f32x2*)&w2[jj * 2];
    }
    f32x2 bias_b2 = *(const f32x2*)b2;

    f32x2* mytb = (f32x2*)&tbuf[w * 2176];
    f32x2 sc[4];

    // ---- CPB: 4 sub-rounds, ZERO barriers (register A-frags + wave-private LDS transpose)
    for (int ii = 0; ii < 4; ++ii) {
        int i = i0 + ii;
        int wq_ = i & 15, hq = (i >> 4) & 15, fq = i >> 8;
        float cq0 = 2.f * fq / 3.f - 1.f;
        float cq1 = 2.f * hq / 15.f - 1.f;
        float cq2 = 2.f * wq_ / 15.f - 1.f;

        float t0[4], t1[4], t2[4];
        #pragma unroll
        for (int mt = 0; mt < 4; ++mt) {
            float p0 = cq0 - g0r[mt];
            float p1 = cq1 - g1r[mt];
            float p2 = cq2 - g2r[mt];
            t0[mt] = copysignf(__logf(1.f + fabsf(p0)), p0);
            t1[mt] = copysignf(__logf(1.f + fabsf(p1)), p1);
            t2[mt] = copysignf(__logf(1.f + fabsf(p2)), p2);
        }

        f32x4 acc[4][4] = {};
        #pragma unroll
        for (int kc = 0; kc < 2; ++kc) {
            int d0 = kc * 32 + quad * 8;
            f32x2 w0a[4], w0b[4], w0c[4], b0p[4];
            #pragma unroll
            for (int pr = 0; pr < 4; ++pr) {
                w0a[pr] = *(const f32x2*)&w0[d0 + 2 * pr];
                w0b[pr] = *(const f32x2*)&w0[64 + d0 + 2 * pr];
                w0c[pr] = *(const f32x2*)&w0[128 + d0 + 2 * pr];
                b0p[pr] = *(const f32x2*)&b0[d0 + 2 * pr];
            }
            #pragma unroll
            for (int mt = 0; mt < 4; ++mt) {
                unsigned int pk[4];
                #pragma unroll
                for (int pr = 0; pr < 4; ++pr) {
                    f32x2 z = b0p[pr];
                    z += t0[mt] * w0a[pr];
                    z += t1[mt] * w0b[pr];
                    z += t2[mt] * w0c[pr];
                    z.x = fmaxf(z.x, 0.f); z.y = fmaxf(z.y, 0.f);
                    pk[pr] = pack_bf2(z);
                }
                uint4 afu = make_uint4(pk[0], pk[1], pk[2], pk[3]);
                bf16x8 af = *(bf16x8*)&afu;
                #pragma unroll
                for (int nt = 0; nt < 4; ++nt)
                    acc[mt][nt] = __builtin_amdgcn_mfma_f32_16x16x32_bf16(
                        af, *(bf16x8*)&bfr[kc][nt], acc[mt][nt], 0, 0, 0);
            }
        }

        // epilogue: relu(h1+b1)@w2 partials -> wave-private LDS transpose (no barrier)
        #pragma unroll
        for (int mt = 0; mt < 4; ++mt)
            #pragma unroll
            for (int reg = 0; reg < 4; ++reg) {
                f32x2 pp = {0.f, 0.f};
                #pragma unroll
                for (int nt = 0; nt < 4; ++nt) {
                    float hv = fmaxf(acc[mt][nt][reg] + b1v[nt], 0.f);
                    pp += hv * w2v[nt];
                }
                mytb[(mt * 16 + quad * 4 + reg) * 17 + col] = pp;
            }
        f32x2 bias2 = bias_b2;
        {
            const f32x2* pr2 = mytb + lane * 17;
            #pragma unroll
            for (int c = 0; c < 16; ++c) bias2 += pr2[c];
        }
        sc[ii] = bias2;
    }
    __syncthreads();   // protect qsL cross-wave reads + attL alias of tbuf

    // ---- QK^T batched over 4 i's ----
    {
        const f32x2* kp = (const f32x2*)kk2 + (size_t)(bg * 64) * PJ + j;
        #pragma unroll 4
        for (int d = 0; d < 64; ++d) {
            f32x2 kv2 = kp[(size_t)d * PJ];
            #pragma unroll
            for (int ii = 0; ii < 4; ++ii) {
                f32x2 qv = *(const f32x2*)&qsL[ii * 128 + d * 2];
                sc[ii] += qv * kv2;
            }
        }
    }
    #pragma unroll
    for (int ii = 0; ii < 4; ++ii) {
        attL[ii * 256 + j] = sc[ii].x;
        attL[ii * 256 + 128 + j] = sc[ii].y;
    }
    __syncthreads();

    #pragma unroll
    for (int ii = 0; ii < 4; ++ii) {
        float a0 = attL[ii * 256 + w * 128 + lane];
        float a1 = attL[ii * 256 + w * 128 + 64 + lane];
        float mx = fmaxf(a0, a1);
        #pragma unroll
        for (int off = 32; off; off >>= 1) mx = fmaxf(mx, __shfl_xor(mx, off));
        float ex = __expf(a0 - mx) + __expf(a1 - mx);
        #pragma unroll
        for (int off = 32; off; off >>= 1) ex += __shfl_xor(ex, off);
        if (lane == 0) { redA[ii * 4 + w * 2] = mx; redA[ii * 4 + w * 2 + 1] = ex; }
    }
    __syncthreads();
    #pragma unroll
    for (int ii = 0; ii < 4; ++ii) {
        float p0n = __expf(sc[ii].x - redA[ii * 4 + 0]) * (1.f / redA[ii * 4 + 1]);
        float p1n = __expf(sc[ii].y - redA[ii * 4 + 2]) * (1.f / redA[ii * 4 + 3]);
        attL[ii * 256 + j] = p0n;
        attL[ii * 256 + 128 + j] = p1n;
    }
    __syncthreads();

    // ---- attn * V batched: thread (e=w, d=lane), V row reused 4x ----
    {
        const f32x2* vp = (const f32x2*)vvT2 + (size_t)(bg * 64) * ODIM + tid;
        f32x2 oacc[4] = {};
        #pragma unroll 4
        for (int jp = 0; jp < 64; ++jp) {
            f32x2 vv2 = vp[(size_t)jp * ODIM];
            #pragma unroll
            for (int ii = 0; ii < 4; ++ii) {
                f32x2 ap2 = *(const f32x2*)&attL[ii * 256 + w * 128 + jp * 2];
                oacc[ii] += ap2 * vv2;
            }
        }
        #pragma unroll
        for (int ii = 0; ii < 4; ++ii)
            outh[((size_t)b * PQ + i0 + ii) * INNERC + g * 128 + tid] =
                oacc[ii].x + oacc[ii].y;
    }
}

// ---------------- final projection, 8 outputs/thread, contiguous reads ---------
__global__ void k_out(const float* __restrict__ outh, const float* __restrict__ wo,
                      const float* __restrict__ bo, float* __restrict__ out) {
    int t = blockIdx.x * 256 + threadIdx.x;   // 2*32*1024 = 65536
    int p = t & 1023;
    int og = (t >> 10) & 31;
    int b = t >> 15;
    int o0 = og * 8;
    const float* hp = outh + ((size_t)b * PQ + p) * INNERC;
    const float* wp = wo + (size_t)o0 * INNERC;
    float acc[8];
    #pragma unroll
    for (int k = 0; k < 8; ++k) acc[k] = bo[o0 + k];
    #pragma unroll 4
    for (int c = 0; c < INNERC; c += 4) {
        float4 hv = *(const float4*)&hp[c];
        #pragma unroll
        for (int k = 0; k < 8; ++k) {
            const float* wr = &wp[k * INNERC + c];
            acc[k] += hv.x * wr[0] + hv.y * wr[1] + hv.z * wr[2] + hv.w * wr[3];
        }
    }
    #pragma unroll
    for (int k = 0; k < 8; ++k)
        out[(size_t)(b * DIMC + o0 + k) * PQ + p] = acc[k];
}

extern "C" void kernel_launch(void* const* d_in, const int* in_sizes, int n_in,
                              void* d_out, int out_size, void* d_ws, size_t ws_size,
                              hipStream_t stream) {
    const float* x   = (const float*)d_in[0];
    const float* wq  = (const float*)d_in[1];
    const float* wk  = (const float*)d_in[2];
    const float* wv  = (const float*)d_in[3];
    const float* dww = (const float*)d_in[4];
    const float* dwb = (const float*)d_in[5];
    const float* pw  = (const float*)d_in[6];
    const float* w0  = (const float*)d_in[7];
    const float* b0  = (const float*)d_in[8];
    const float* w1  = (const float*)d_in[9];
    const float* b1  = (const float*)d_in[10];
    const float* w2  = (const float*)d_in[11];
    const float* b2  = (const float*)d_in[12];
    const float* wo  = (const float*)d_in[13];
    const float* bo  = (const float*)d_in[14];
    float* out = (float*)d_out;

    float* ws_f = (float*)d_ws;
    uint4* wb   = (uint4*)ws_f;          // 2048 floats
    float* q    = ws_f + 2048;           // 1048576
    float* act  = q + 1048576;           // 131072
    float* gkv  = act + 131072;          // 3072
    float* kk2  = gkv + 3072;            // 131072
    float* vvT2 = kk2 + 131072;          // 131072
    float* outh = vvT2 + 131072;         // 1048576

    k_qdw<<<258, 256, 0, stream>>>(x, wq, dww, dwb, w1, q, act, wb);
    k_kvf<<<1024, 128, 0, stream>>>(act, pw, x, wk, wv, gkv, kk2, vvT2);
    k_attn<<<2048, 128, 0, stream>>>(q, kk2, vvT2, gkv, w0, b0, wb, b1, w2, b2, outh);
    k_out<<<256, 256, 0, stream>>>(outh, wo, bo, out);
}